// Round 11
// baseline (203.449 us; speedup 1.0000x reference)
//
#include <hip/hip_runtime.h>
#include <hip/hip_bf16.h>

// Causal attention, S=4096, d=1024, fp32 in/out.
// bf16 MFMA for projections and PV; fp8 e4m3 MFMA (BK=128B) for scores only.
// fp8 placement (round-6): V/P fp8 leak raw e4m3 error into O; Q/K fp8 error
// cancels under renormalization (measured +0.02 absmax). Budget spent.
// NO device-scope fences anywhere: on gfx950 __threadfence = per-XCD L2
// writeback/invalidate; round-9's fused reduce (768 fences) ran 10x slower.
//
// Round-11:
//  - fp8 fragment reads switched ds_read_b64 -> ds_read_b128 + cndmask half-
//    select. Round-10 showed 2.16M SQ_LDS_BANK_CONFLICT (~4 cyc/inst): b64 in
//    16-lane phases can only reach 8/16 bank-pairs at 16B swizzle granularity.
//    The b128 pattern is the bf16 tile's (measured conflict-free).
//  - Vt projection split between k_qkv and k_sv (640/656 blocks, 2.5/CU each;
//    round-10 had 512/784 -> k_qkv underfilled at 2/CU).
//
// Workspace (256 MiB):
//   [0,8M)    x_bf  [4096,1024] bf16
//   [8M,12M)  Wqk   [2048,1024] bf16 (Wq rows 0..1023, Wk rows 1024..2047)
//   [12M,14M) Wv_bf [1024,1024] bf16
//   [14M,22M) QK    [4096,2048] fp8  (Q cols 0..1023, K cols 1024..2047)
//   [22M,30M) Vt    [1024,4096] bf16 (V^T, computed directly as Wv @ x^T)
//   [30M,62M) P~    [4096,4096] bf16 (exp(s/32), masked, unnormalized)
//   [62M,62.5M) rowsum_part [4096][32] fp32 (slot bn; dead slots zeroed)
//   [64M,100M) PV fp32 partials (72 multi-split groups x 8 bn x 64 KB)

typedef __bf16 bf16_t;
typedef __bf16 bf16x4v __attribute__((ext_vector_type(4)));
typedef __bf16 bf16x8 __attribute__((ext_vector_type(8)));
typedef float f32x4 __attribute__((ext_vector_type(4)));
typedef unsigned char u8;
typedef long long i64_t;
typedef long long i64x2 __attribute__((ext_vector_type(2)));

#define AS1 __attribute__((address_space(1)))
#define AS3 __attribute__((address_space(3)))

__device__ __forceinline__ void async_copy16(const void* g, void* l) {
    // 16B/lane direct global->LDS; LDS dest = wave-uniform base + lane*16
    __builtin_amdgcn_global_load_lds((AS1 void*)(g), (AS3 void*)(l), 16, 0, 0);
}

__device__ __forceinline__ u8 f32_to_fp8(float v) {
    // OCP e4m3 on gfx950 (HW conversion); layout validated in round 6
    return (u8)(__builtin_amdgcn_cvt_pk_fp8_f32(v, v, 0, false) & 0xff);
}

__device__ __forceinline__ void store_conv(float* p, float v) { *p = v; }
__device__ __forceinline__ void store_conv(bf16_t* p, float v) { *p = (bf16_t)v; }
__device__ __forceinline__ void store_conv(u8* p, float v) { *p = f32_to_fp8(v); }

// Sum of 32 consecutive floats (8x float4), for 1/rowsum computation.
__device__ __forceinline__ float sum32(const float* p) {
    const f32x4* v = (const f32x4*)p;
    float s = 0.f;
#pragma unroll
    for (int u = 0; u < 8; ++u) {
        f32x4 a = v[u];
        s += a[0] + a[1] + a[2] + a[3];
    }
    return s;
}

// ---------------- bf16 tile: BM=128, BN=128, BK=64 ------------------------
// XOR-swizzled LDS (16B chunk b of row r holds k-chunk b^(r&7)) -> conflict-
// free staging writes and ds_read_b128 fragment reads. kb in [kb0,kb1).
// EPI 0: C = v*alpha | EPI 2: C = v * inv[row] (inv indexed by tile-local row)
template <int EPI, typename OutT>
__device__ __forceinline__ void gemm_tile_bf16(const bf16_t* __restrict__ A, int lda,
                                               const bf16_t* __restrict__ B, int ldb,
                                               OutT* __restrict__ C, int ldc,
                                               int kb0, int kb1, float alpha,
                                               bf16_t* __restrict__ As,
                                               bf16_t* __restrict__ Bs,
                                               const float* __restrict__ inv) {
    constexpr int BK = 64;
    const int tid = threadIdx.x;
    const int lane = tid & 63, wave = tid >> 6;
    const int wm = wave >> 1, wn = wave & 1;
    const int q = lane >> 4, l16 = lane & 15;

    f32x4 acc[4][4] = {};

    const bf16_t* aSrc[4];
    const bf16_t* bSrc[4];
    int ldsOff[4];
#pragma unroll
    for (int it = 0; it < 4; ++it) {
        int c = it * 256 + tid;
        int r = c >> 3, b = c & 7;
        int sb = b ^ (r & 7);
        aSrc[it] = A + (size_t)r * lda + sb * 8;
        bSrc[it] = B + (size_t)r * ldb + sb * 8;
        ldsOff[it] = c * 8;
    }

    for (int kb = kb0; kb < kb1; ++kb) {
        const int k0 = kb * BK;
#pragma unroll
        for (int it = 0; it < 4; ++it) async_copy16(aSrc[it] + k0, &As[ldsOff[it]]);
#pragma unroll
        for (int it = 0; it < 4; ++it) async_copy16(bSrc[it] + k0, &Bs[ldsOff[it]]);
        __syncthreads();

#pragma unroll
        for (int k2 = 0; k2 < 2; ++k2) {
            bf16x8 af[4], bfr[4];
#pragma unroll
            for (int mt = 0; mt < 4; ++mt) {
                int m = wm * 64 + mt * 16 + l16;
                int blk = (k2 * 4 + q) ^ (m & 7);
                af[mt] = *(const bf16x8*)&As[m * BK + blk * 8];
            }
#pragma unroll
            for (int nt = 0; nt < 4; ++nt) {
                int nn = wn * 64 + nt * 16 + l16;
                int blk = (k2 * 4 + q) ^ (nn & 7);
                bfr[nt] = *(const bf16x8*)&Bs[nn * BK + blk * 8];
            }
#pragma unroll
            for (int mt = 0; mt < 4; ++mt)
#pragma unroll
                for (int nt = 0; nt < 4; ++nt)
                    acc[mt][nt] = __builtin_amdgcn_mfma_f32_16x16x32_bf16(
                        af[mt], bfr[nt], acc[mt][nt], 0, 0, 0);
        }
        __syncthreads();
    }

    // C/D layout: col = lane&15, row = (lane>>4)*4 + reg
    const int row0 = wm * 64, col0 = wn * 64;
#pragma unroll
    for (int mt = 0; mt < 4; ++mt)
#pragma unroll
        for (int nt = 0; nt < 4; ++nt)
#pragma unroll
            for (int r = 0; r < 4; ++r) {
                int lr = row0 + mt * 16 + q * 4 + r;
                float v = acc[mt][nt][r];
                v = (EPI == 2) ? v * inv[lr] : v * alpha;
                store_conv(&C[(size_t)lr * ldc + col0 + nt * 16 + l16], v);
            }
}

// ---------------- fp8 scores tile: 128x128, BK=128 bytes ------------------
// mfma_f32_16x16x32_fp8_fp8 (i64 frags, 8B/lane: m=lane&15, k=quad*8+j).
// LDS row = 128B = 8 16B chunks, chunk cb of row r at slot cb^(r&7).
// Fragment reads are ds_read_b128 of the full chunk + cndmask half-select
// (b64 reads at 16B swizzle granularity = 2-way phase conflict, round-10).
// Epilogue: C = bf16(exp(v*alpha)) causally masked + per-row partial sums
// into `partial` (pre-offset, stride 32 floats).
__device__ __forceinline__ void scores_tile_fp8(const u8* __restrict__ A, int lda,
                                                const u8* __restrict__ B, int ldb,
                                                bf16_t* __restrict__ C, int ldc,
                                                float alpha,
                                                u8* __restrict__ As, u8* __restrict__ Bs,
                                                float* __restrict__ partial,
                                                int gr0, int gc0,
                                                float* __restrict__ sred) {
    const int tid = threadIdx.x;
    const int lane = tid & 63, wave = tid >> 6;
    const int wm = wave >> 1, wn = wave & 1;
    const int q = lane >> 4, l16 = lane & 15;
    const int qh = q & 1;  // which 8B half of the 16B chunk this lane needs

    f32x4 acc[4][4] = {};

    const u8* aSrc[4];
    const u8* bSrc[4];
    int ldsOff[4];
#pragma unroll
    for (int it = 0; it < 4; ++it) {
        int c = it * 256 + tid;
        int r = c >> 3, b = c & 7;
        int sb = b ^ (r & 7);
        aSrc[it] = A + (size_t)r * lda + sb * 16;
        bSrc[it] = B + (size_t)r * ldb + sb * 16;
        ldsOff[it] = c * 16;
    }

    for (int kb = 0; kb < 8; ++kb) {
        const int k0 = kb * 128;
#pragma unroll
        for (int it = 0; it < 4; ++it) async_copy16(aSrc[it] + k0, &As[ldsOff[it]]);
#pragma unroll
        for (int it = 0; it < 4; ++it) async_copy16(bSrc[it] + k0, &Bs[ldsOff[it]]);
        __syncthreads();

#pragma unroll
        for (int k2 = 0; k2 < 4; ++k2) {
            i64_t af[4], bfr[4];
            const int cb = 2 * k2 + (q >> 1);
#pragma unroll
            for (int mt = 0; mt < 4; ++mt) {
                int m = wm * 64 + mt * 16 + l16;
                i64x2 v = *(const i64x2*)&As[m * 128 + ((cb ^ (m & 7)) << 4)];
                af[mt] = qh ? v.y : v.x;
            }
#pragma unroll
            for (int nt = 0; nt < 4; ++nt) {
                int nn = wn * 64 + nt * 16 + l16;
                i64x2 v = *(const i64x2*)&Bs[nn * 128 + ((cb ^ (nn & 7)) << 4)];
                bfr[nt] = qh ? v.y : v.x;
            }
#pragma unroll
            for (int mt = 0; mt < 4; ++mt)
#pragma unroll
                for (int nt = 0; nt < 4; ++nt)
                    acc[mt][nt] = __builtin_amdgcn_mfma_f32_16x16x32_fp8_fp8(
                        af[mt], bfr[nt], acc[mt][nt], 0, 0, 0);
        }
        __syncthreads();
    }

    // Epilogue: P = exp(v*alpha) masked, bf16; per-row sums via 16-lane shfl.
    const int row0 = wm * 64, col0 = wn * 64;
    float esum[4][4];
#pragma unroll
    for (int mt = 0; mt < 4; ++mt)
#pragma unroll
        for (int r = 0; r < 4; ++r) esum[mt][r] = 0.f;
#pragma unroll
    for (int mt = 0; mt < 4; ++mt)
#pragma unroll
        for (int nt = 0; nt < 4; ++nt)
#pragma unroll
            for (int r = 0; r < 4; ++r) {
                int lr = row0 + mt * 16 + q * 4 + r;
                int lc = col0 + nt * 16 + l16;
                float p = (gc0 + lc > gr0 + lr) ? 0.f : __expf(acc[mt][nt][r] * alpha);
                esum[mt][r] += p;
                C[(size_t)lr * ldc + lc] = (bf16_t)p;
            }
#pragma unroll
    for (int mt = 0; mt < 4; ++mt)
#pragma unroll
        for (int r = 0; r < 4; ++r) {
#pragma unroll
            for (int off = 1; off < 16; off <<= 1)
                esum[mt][r] += __shfl_xor(esum[mt][r], off, 64);
            if (l16 == 0) sred[(row0 + mt * 16 + q * 4 + r) * 2 + wn] = esum[mt][r];
        }
    __syncthreads();
    if (tid < 128) partial[(size_t)tid * 32] = sred[tid * 2] + sred[tid * 2 + 1];
}

// Projections, 640 blocks (2.5/CU), 16 bf16 kb-iters each:
//   b in [0,512):   QK = x @ [Wq;Wk]^T [4096,2048] -> fp8
//   b in [512,640): Vt = Wv @ x^T, bn 0..15 half (other half in k_sv)
__global__ __launch_bounds__(256) void k_qkv(const bf16_t* __restrict__ xb,
                                             const bf16_t* __restrict__ wqk,
                                             const bf16_t* __restrict__ wvb,
                                             u8* __restrict__ qk,
                                             bf16_t* __restrict__ vt) {
    __shared__ __attribute__((aligned(16))) bf16_t As[128 * 64];
    __shared__ __attribute__((aligned(16))) bf16_t Bs[128 * 64];
    int b = blockIdx.x;
    if (b < 512) {
        int bm = b & 31, bn = b >> 5;  // bn 0..15
        gemm_tile_bf16<0, u8>(xb + (size_t)bm * 128 * 1024, 1024,
                              wqk + (size_t)bn * 128 * 1024, 1024,
                              qk + (size_t)bm * 128 * 2048 + bn * 128, 2048,
                              0, 16, 1.f, As, Bs, nullptr);
    } else {
        int t = b - 512;
        int bm = t & 7, bn = t >> 3;  // bn 0..15
        gemm_tile_bf16<0, bf16_t>(wvb + (size_t)bm * 128 * 1024, 1024,
                                  xb + (size_t)bn * 128 * 1024, 1024,
                                  vt + (size_t)bm * 128 * 4096 + bn * 128, 4096,
                                  0, 16, 1.f, As, Bs, nullptr);
    }
}

// Merged dispatch, 656 blocks (2.56/CU):
//   b in [0,128):   Vt = Wv @ x^T, bn 16..31 half (16 bf16 iters)
//   b in [128,656): P~ = exp((Q@K^T)/32) causal 128x128 tiles, fp8, 8 iters;
//     compact tri grid t = bm(bm+1)/2 + bn (528 tiles); emits per-row partial
//     sums; diagonal tiles (bn==bm) zero dead slots [bm+1,32).
__global__ __launch_bounds__(256) void k_sv(const bf16_t* __restrict__ xb,
                                            const bf16_t* __restrict__ wvb,
                                            const u8* __restrict__ qk,
                                            bf16_t* __restrict__ vt,
                                            bf16_t* __restrict__ P,
                                            float* __restrict__ rowsum_part) {
    __shared__ __attribute__((aligned(16))) char smem[33 * 1024 + 1024];
    int b = blockIdx.x;
    if (b < 128) {
        bf16_t* As = (bf16_t*)smem;
        bf16_t* Bs = (bf16_t*)(smem + 16384);
        int bm = b & 7, bn = 16 + (b >> 3);  // bn 16..31
        gemm_tile_bf16<0, bf16_t>(wvb + (size_t)bm * 128 * 1024, 1024,
                                  xb + (size_t)bn * 128 * 1024, 1024,
                                  vt + (size_t)bm * 128 * 4096 + bn * 128, 4096,
                                  0, 16, 1.f, As, Bs, nullptr);
        return;
    }
    u8* As = (u8*)smem;
    u8* Bs = (u8*)(smem + 16384);
    float* sred = (float*)(smem + 32768);
    int t = b - 128;  // 0..527
    int bm = (int)((sqrtf(8.f * (float)t + 1.f) - 1.f) * 0.5f);
    while (bm * (bm + 1) / 2 > t) --bm;
    while ((bm + 1) * (bm + 2) / 2 <= t) ++bm;
    int bn = t - bm * (bm + 1) / 2;  // 0..bm
    scores_tile_fp8(qk + (size_t)bm * 128 * 2048, 2048,
                    qk + 1024 + (size_t)bn * 128 * 2048, 2048,
                    P + (size_t)bm * 128 * 4096 + bn * 128, 4096,
                    0.03125f, As, Bs,
                    rowsum_part + (size_t)bm * 128 * 32 + bn,
                    bm * 128, bn * 128, sred);
    if (bn == bm) {  // zero dead rowsum slots for this row block
        float* rp = rowsum_part + (size_t)bm * 128 * 32;
        int tid = threadIdx.x;
        for (int r = tid >> 4; r < 128; r += 16)
            for (int u = bm + 1 + (tid & 15); u < 32; u += 16)
                rp[r * 32 + u] = 0.f;
    }
}

// O = (P~ @ V) * diag(1/rowsum), bf16, BK=64: nk = 2(bm+1) iters.
// Split-K chunk 16: 80 (bm,s) groups x 8 bn = 640 compact blocks (2.5/CU).
// Single-split (bm<=7) computes 1/rowsum into LDS and stores direct;
// multi-split writes fp32 partials for k_reduce.
__global__ __launch_bounds__(256) void k_pv(const bf16_t* __restrict__ P,
                                            const bf16_t* __restrict__ vt,
                                            const float* __restrict__ rowsum_part,
                                            float* __restrict__ out,
                                            float* __restrict__ partials) {
    __shared__ __attribute__((aligned(16))) bf16_t As[128 * 64];
    __shared__ __attribute__((aligned(16))) bf16_t Bs[128 * 64];
    __shared__ float sInv[128];
    int b = blockIdx.x;
    int bn = b & 7, g = b >> 3;
    int bm, s, ns;
    if (g < 8)       { bm = g;                 s = 0;            ns = 1; }
    else if (g < 24) { bm = 8 + (g - 8) / 2;   s = (g - 8) % 2;  ns = 2; }
    else if (g < 48) { bm = 16 + (g - 24) / 3; s = (g - 24) % 3; ns = 3; }
    else             { bm = 24 + (g - 48) / 4; s = (g - 48) % 4; ns = 4; }
    int nk = 2 * (bm + 1);
    int kb0 = s * nk / ns;
    int kb1 = (s + 1) * nk / ns;

    const bf16_t* A = P + (size_t)bm * 128 * 4096;
    const bf16_t* B = vt + (size_t)bn * 128 * 4096;
    if (ns == 1) {
        int tid = threadIdx.x;
        if (tid < 128)
            sInv[tid] = 1.f / sum32(rowsum_part + (size_t)(bm * 128 + tid) * 32);
        // visibility of sInv covered by the K-loop's __syncthreads (nk >= 2)
        gemm_tile_bf16<2, float>(A, 4096, B, 4096,
                                 out + (size_t)bm * 128 * 1024 + bn * 128, 1024,
                                 kb0, kb1, 1.f, As, Bs, sInv);
    } else {
        int cum = (bm < 16) ? (bm - 8) * 2
                : (bm < 24) ? 16 + (bm - 16) * 3
                            : 40 + (bm - 24) * 4;
        gemm_tile_bf16<0, float>(A, 4096, B, 4096,
                                 partials + ((size_t)(cum + s) * 8 + bn) * 16384, 128,
                                 kb0, kb1, 1.f, As, Bs, nullptr);
    }
}

// out tiles for bm in [8,31]: sum 2..4 fp32 partials, scale by 1/rowsum.
// Compact 3072 blocks: t = b%192 -> (bm-8, bn); p = b/192 -> tile 16th
// (8 rows x 128 cols per block); float4/thread.
__global__ __launch_bounds__(256) void k_reduce(const float* __restrict__ partials,
                                                const float* __restrict__ rowsum_part,
                                                float* __restrict__ out) {
    int b = blockIdx.x;
    int t = b % 192, p = b / 192;
    int bm = t % 24 + 8, bn = t / 24;
    int ns = (bm < 16) ? 2 : (bm < 24) ? 3 : 4;
    int cum = (bm < 16) ? (bm - 8) * 2
            : (bm < 24) ? 16 + (bm - 16) * 3
                        : 40 + (bm - 24) * 4;
    __shared__ float sInv[8];
    int tid = threadIdx.x;
    if (tid < 8) {
        int row = bm * 128 + p * 8 + tid;
        sInv[tid] = 1.f / sum32(rowsum_part + (size_t)row * 32);
    }
    __syncthreads();

    int idx = p * 1024 + tid * 4;
    int lr = idx >> 7, lc = idx & 127;
    float sx = 0.f, sy = 0.f, sz = 0.f, sw = 0.f;
    for (int u = 0; u < ns; ++u) {
        const float4 v = *(const float4*)(partials + ((size_t)(cum + u) * 8 + bn) * 16384 + idx);
        sx += v.x; sy += v.y; sz += v.z; sw += v.w;
    }
    float inv = sInv[lr - p * 8];
    float4 o = {sx * inv, sy * inv, sz * inv, sw * inv};
    *(float4*)(out + (size_t)(bm * 128 + lr) * 1024 + bn * 128 + lc) = o;
}

// fp32 -> bf16 casts: x -> x_bf, Wq|Wk -> Wqk (concat), Wv -> Wv_bf.
__global__ __launch_bounds__(256) void cast_to_bf16(const float* __restrict__ x,
                                                    const float* __restrict__ Wq,
                                                    const float* __restrict__ Wk,
                                                    const float* __restrict__ Wv,
                                                    bf16_t* __restrict__ xb,
                                                    bf16_t* __restrict__ wqk,
                                                    bf16_t* __restrict__ wv) {
    const int NX = (4096 * 1024) / 4;
    const int NW = (1024 * 1024) / 4;
    int idx = blockIdx.x * 256 + threadIdx.x;
    const float* src;
    bf16_t* dst;
    int off;
    if (idx < NX) {
        src = x; dst = xb; off = idx;
    } else if (idx < NX + NW) {
        src = Wq; dst = wqk; off = idx - NX;
    } else if (idx < NX + 2 * NW) {
        src = Wk; dst = wqk + (size_t)NW * 4; off = idx - NX - NW;
    } else {
        src = Wv; dst = wv; off = idx - NX - 2 * NW;
    }
    float4 f = ((const float4*)src)[off];
    bf16x4v o;
    o.x = (bf16_t)f.x; o.y = (bf16_t)f.y; o.z = (bf16_t)f.z; o.w = (bf16_t)f.w;
    *(bf16x4v*)(dst + (size_t)off * 4) = o;
}

extern "C" void kernel_launch(void* const* d_in, const int* in_sizes, int n_in,
                              void* d_out, int out_size, void* d_ws, size_t ws_size,
                              hipStream_t stream) {
    (void)in_sizes; (void)n_in; (void)out_size; (void)ws_size;
    const float* x  = (const float*)d_in[0];
    const float* Wq = (const float*)d_in[1];
    const float* Wk = (const float*)d_in[2];
    const float* Wv = (const float*)d_in[3];
    float* out = (float*)d_out;

    char* ws = (char*)d_ws;
    bf16_t* xb   = (bf16_t*)(ws + (size_t)0);
    bf16_t* wqk  = (bf16_t*)(ws + ((size_t)8 << 20));
    bf16_t* wvb  = (bf16_t*)(ws + ((size_t)12 << 20));
    u8*     qk   = (u8*)(ws + ((size_t)14 << 20));
    bf16_t* vt   = (bf16_t*)(ws + ((size_t)22 << 20));
    bf16_t* P    = (bf16_t*)(ws + ((size_t)30 << 20));
    float* rowsp = (float*)(ws + ((size_t)62 << 20));
    float* parts = (float*)(ws + ((size_t)64 << 20));

    cast_to_bf16<<<7168, 256, 0, stream>>>(x, Wq, Wk, Wv, xb, wqk, wvb);

    // QK (fp8) + half of Vt (640 blocks, 2.5/CU)
    k_qkv<<<640, 256, 0, stream>>>(xb, wqk, wvb, qk, vt);

    // Other half of Vt + P~ = exp((Q@K^T)/32) causal 128x128 (656 blocks)
    k_sv<<<656, 256, 0, stream>>>(xb, wvb, qk, vt, P, rowsp);

    // out = (P~ @ V) * diag(1/rowsum): split-K chunk 16 + partial reduction
    k_pv<<<640, 256, 0, stream>>>(P, vt, rowsp, out, parts);
    k_reduce<<<3072, 256, 0, stream>>>(parts, rowsp, out);
}

// Round 12
// 201.084 us; speedup vs baseline: 1.0118x; 1.0118x over previous
//
#include <hip/hip_runtime.h>
#include <hip/hip_bf16.h>

// Causal attention, S=4096, d=1024, fp32 in/out.
// bf16 MFMA for projections and PV; fp8 e4m3 MFMA (BK=128B) for scores only.
// fp8 placement (round-6): V/P fp8 leak raw e4m3 error into O; Q/K fp8 error
// cancels under renormalization (measured +0.02 absmax). Budget spent.
// NO device-scope fences (round-9: __threadfence = per-XCD L2 flush, 10x).
//
// Round-12: critical-path packing. Blocks dispatch round-robin over 256 CUs;
// kernel time = max-per-CU (blocks x iters), not average (round-11: 640-block
// grid = 2.5/CU put 3 long blocks on half the CUs -> +10us vs 512 uniform).
//  - k_qkv = QK + ALL of Vt = 768 blocks, exactly 3/CU, uniform 16-iter blocks
//  - k_sc  = 528 pure score tiles (128x128 fp8, 8 iters each)
//  - k_pv groups ordered by descending split length so the 3rd dispatch round
//    carries only short blocks (worst CU 48 -> ~45 iters)
//  - fp8 fragment reads stay ds_read_b128 + half-select (round-11, -2us).
//    NOTE: SQ_LDS_BANK_CONFLICT 2.16M is invariant under read width -> it is
//    staging-DMA 2-way aliasing (cheap), not the reads. Stop chasing it.
//
// Workspace (256 MiB):
//   [0,8M)    x_bf  [4096,1024] bf16
//   [8M,12M)  Wqk   [2048,1024] bf16 (Wq rows 0..1023, Wk rows 1024..2047)
//   [12M,14M) Wv_bf [1024,1024] bf16
//   [14M,22M) QK    [4096,2048] fp8  (Q cols 0..1023, K cols 1024..2047)
//   [22M,30M) Vt    [1024,4096] bf16 (V^T, computed directly as Wv @ x^T)
//   [30M,62M) P~    [4096,4096] bf16 (exp(s/32), masked, unnormalized)
//   [62M,62.5M) rowsum_part [4096][32] fp32 (slot bn; dead slots zeroed)
//   [64M,100M) PV fp32 partials (72 multi-split groups x 8 bn x 64 KB)

typedef __bf16 bf16_t;
typedef __bf16 bf16x4v __attribute__((ext_vector_type(4)));
typedef __bf16 bf16x8 __attribute__((ext_vector_type(8)));
typedef float f32x4 __attribute__((ext_vector_type(4)));
typedef unsigned char u8;
typedef long long i64_t;
typedef long long i64x2 __attribute__((ext_vector_type(2)));

#define AS1 __attribute__((address_space(1)))
#define AS3 __attribute__((address_space(3)))

__device__ __forceinline__ void async_copy16(const void* g, void* l) {
    // 16B/lane direct global->LDS; LDS dest = wave-uniform base + lane*16
    __builtin_amdgcn_global_load_lds((AS1 void*)(g), (AS3 void*)(l), 16, 0, 0);
}

__device__ __forceinline__ u8 f32_to_fp8(float v) {
    // OCP e4m3 on gfx950 (HW conversion); layout validated in round 6
    return (u8)(__builtin_amdgcn_cvt_pk_fp8_f32(v, v, 0, false) & 0xff);
}

__device__ __forceinline__ void store_conv(float* p, float v) { *p = v; }
__device__ __forceinline__ void store_conv(bf16_t* p, float v) { *p = (bf16_t)v; }
__device__ __forceinline__ void store_conv(u8* p, float v) { *p = f32_to_fp8(v); }

// Sum of 32 consecutive floats (8x float4), for 1/rowsum computation.
__device__ __forceinline__ float sum32(const float* p) {
    const f32x4* v = (const f32x4*)p;
    float s = 0.f;
#pragma unroll
    for (int u = 0; u < 8; ++u) {
        f32x4 a = v[u];
        s += a[0] + a[1] + a[2] + a[3];
    }
    return s;
}

// ---------------- bf16 tile: BM=128, BN=128, BK=64 ------------------------
// XOR-swizzled LDS (16B chunk b of row r holds k-chunk b^(r&7)) -> conflict-
// free staging writes and ds_read_b128 fragment reads. kb in [kb0,kb1).
// EPI 0: C = v*alpha | EPI 2: C = v * inv[row] (inv indexed by tile-local row)
template <int EPI, typename OutT>
__device__ __forceinline__ void gemm_tile_bf16(const bf16_t* __restrict__ A, int lda,
                                               const bf16_t* __restrict__ B, int ldb,
                                               OutT* __restrict__ C, int ldc,
                                               int kb0, int kb1, float alpha,
                                               bf16_t* __restrict__ As,
                                               bf16_t* __restrict__ Bs,
                                               const float* __restrict__ inv) {
    constexpr int BK = 64;
    const int tid = threadIdx.x;
    const int lane = tid & 63, wave = tid >> 6;
    const int wm = wave >> 1, wn = wave & 1;
    const int q = lane >> 4, l16 = lane & 15;

    f32x4 acc[4][4] = {};

    const bf16_t* aSrc[4];
    const bf16_t* bSrc[4];
    int ldsOff[4];
#pragma unroll
    for (int it = 0; it < 4; ++it) {
        int c = it * 256 + tid;
        int r = c >> 3, b = c & 7;
        int sb = b ^ (r & 7);
        aSrc[it] = A + (size_t)r * lda + sb * 8;
        bSrc[it] = B + (size_t)r * ldb + sb * 8;
        ldsOff[it] = c * 8;
    }

    for (int kb = kb0; kb < kb1; ++kb) {
        const int k0 = kb * BK;
#pragma unroll
        for (int it = 0; it < 4; ++it) async_copy16(aSrc[it] + k0, &As[ldsOff[it]]);
#pragma unroll
        for (int it = 0; it < 4; ++it) async_copy16(bSrc[it] + k0, &Bs[ldsOff[it]]);
        __syncthreads();

#pragma unroll
        for (int k2 = 0; k2 < 2; ++k2) {
            bf16x8 af[4], bfr[4];
#pragma unroll
            for (int mt = 0; mt < 4; ++mt) {
                int m = wm * 64 + mt * 16 + l16;
                int blk = (k2 * 4 + q) ^ (m & 7);
                af[mt] = *(const bf16x8*)&As[m * BK + blk * 8];
            }
#pragma unroll
            for (int nt = 0; nt < 4; ++nt) {
                int nn = wn * 64 + nt * 16 + l16;
                int blk = (k2 * 4 + q) ^ (nn & 7);
                bfr[nt] = *(const bf16x8*)&Bs[nn * BK + blk * 8];
            }
#pragma unroll
            for (int mt = 0; mt < 4; ++mt)
#pragma unroll
                for (int nt = 0; nt < 4; ++nt)
                    acc[mt][nt] = __builtin_amdgcn_mfma_f32_16x16x32_bf16(
                        af[mt], bfr[nt], acc[mt][nt], 0, 0, 0);
        }
        __syncthreads();
    }

    // C/D layout: col = lane&15, row = (lane>>4)*4 + reg
    const int row0 = wm * 64, col0 = wn * 64;
#pragma unroll
    for (int mt = 0; mt < 4; ++mt)
#pragma unroll
        for (int nt = 0; nt < 4; ++nt)
#pragma unroll
            for (int r = 0; r < 4; ++r) {
                int lr = row0 + mt * 16 + q * 4 + r;
                float v = acc[mt][nt][r];
                v = (EPI == 2) ? v * inv[lr] : v * alpha;
                store_conv(&C[(size_t)lr * ldc + col0 + nt * 16 + l16], v);
            }
}

// ---------------- fp8 scores tile: 128x128, BK=128 bytes ------------------
// mfma_f32_16x16x32_fp8_fp8 (i64 frags, 8B/lane: m=lane&15, k=quad*8+j).
// LDS row = 128B = 8 16B chunks, chunk cb of row r at slot cb^(r&7).
// Fragment reads: ds_read_b128 of the full chunk + half-select.
// Epilogue: C = bf16(exp(v*alpha)) causally masked + per-row partial sums
// into `partial` (pre-offset, stride 32 floats).
__device__ __forceinline__ void scores_tile_fp8(const u8* __restrict__ A, int lda,
                                                const u8* __restrict__ B, int ldb,
                                                bf16_t* __restrict__ C, int ldc,
                                                float alpha,
                                                u8* __restrict__ As, u8* __restrict__ Bs,
                                                float* __restrict__ partial,
                                                int gr0, int gc0,
                                                float* __restrict__ sred) {
    const int tid = threadIdx.x;
    const int lane = tid & 63, wave = tid >> 6;
    const int wm = wave >> 1, wn = wave & 1;
    const int q = lane >> 4, l16 = lane & 15;
    const int qh = q & 1;  // which 8B half of the 16B chunk this lane needs

    f32x4 acc[4][4] = {};

    const u8* aSrc[4];
    const u8* bSrc[4];
    int ldsOff[4];
#pragma unroll
    for (int it = 0; it < 4; ++it) {
        int c = it * 256 + tid;
        int r = c >> 3, b = c & 7;
        int sb = b ^ (r & 7);
        aSrc[it] = A + (size_t)r * lda + sb * 16;
        bSrc[it] = B + (size_t)r * ldb + sb * 16;
        ldsOff[it] = c * 16;
    }

    for (int kb = 0; kb < 8; ++kb) {
        const int k0 = kb * 128;
#pragma unroll
        for (int it = 0; it < 4; ++it) async_copy16(aSrc[it] + k0, &As[ldsOff[it]]);
#pragma unroll
        for (int it = 0; it < 4; ++it) async_copy16(bSrc[it] + k0, &Bs[ldsOff[it]]);
        __syncthreads();

#pragma unroll
        for (int k2 = 0; k2 < 4; ++k2) {
            i64_t af[4], bfr[4];
            const int cb = 2 * k2 + (q >> 1);
#pragma unroll
            for (int mt = 0; mt < 4; ++mt) {
                int m = wm * 64 + mt * 16 + l16;
                i64x2 v = *(const i64x2*)&As[m * 128 + ((cb ^ (m & 7)) << 4)];
                af[mt] = qh ? v.y : v.x;
            }
#pragma unroll
            for (int nt = 0; nt < 4; ++nt) {
                int nn = wn * 64 + nt * 16 + l16;
                i64x2 v = *(const i64x2*)&Bs[nn * 128 + ((cb ^ (nn & 7)) << 4)];
                bfr[nt] = qh ? v.y : v.x;
            }
#pragma unroll
            for (int mt = 0; mt < 4; ++mt)
#pragma unroll
                for (int nt = 0; nt < 4; ++nt)
                    acc[mt][nt] = __builtin_amdgcn_mfma_f32_16x16x32_fp8_fp8(
                        af[mt], bfr[nt], acc[mt][nt], 0, 0, 0);
        }
        __syncthreads();
    }

    // Epilogue: P = exp(v*alpha) masked, bf16; per-row sums via 16-lane shfl.
    const int row0 = wm * 64, col0 = wn * 64;
    float esum[4][4];
#pragma unroll
    for (int mt = 0; mt < 4; ++mt)
#pragma unroll
        for (int r = 0; r < 4; ++r) esum[mt][r] = 0.f;
#pragma unroll
    for (int mt = 0; mt < 4; ++mt)
#pragma unroll
        for (int nt = 0; nt < 4; ++nt)
#pragma unroll
            for (int r = 0; r < 4; ++r) {
                int lr = row0 + mt * 16 + q * 4 + r;
                int lc = col0 + nt * 16 + l16;
                float p = (gc0 + lc > gr0 + lr) ? 0.f : __expf(acc[mt][nt][r] * alpha);
                esum[mt][r] += p;
                C[(size_t)lr * ldc + lc] = (bf16_t)p;
            }
#pragma unroll
    for (int mt = 0; mt < 4; ++mt)
#pragma unroll
        for (int r = 0; r < 4; ++r) {
#pragma unroll
            for (int off = 1; off < 16; off <<= 1)
                esum[mt][r] += __shfl_xor(esum[mt][r], off, 64);
            if (l16 == 0) sred[(row0 + mt * 16 + q * 4 + r) * 2 + wn] = esum[mt][r];
        }
    __syncthreads();
    if (tid < 128) partial[(size_t)tid * 32] = sred[tid * 2] + sred[tid * 2 + 1];
}

// Projections, 768 blocks (EXACTLY 3/CU, uniform 16 bf16 kb-iters each):
//   b in [0,512):   QK = x @ [Wq;Wk]^T [4096,2048] -> fp8
//   b in [512,768): Vt = Wv @ x^T      [1024,4096] -> bf16
__global__ __launch_bounds__(256) void k_qkv(const bf16_t* __restrict__ xb,
                                             const bf16_t* __restrict__ wqk,
                                             const bf16_t* __restrict__ wvb,
                                             u8* __restrict__ qk,
                                             bf16_t* __restrict__ vt) {
    __shared__ __attribute__((aligned(16))) bf16_t As[128 * 64];
    __shared__ __attribute__((aligned(16))) bf16_t Bs[128 * 64];
    int b = blockIdx.x;
    if (b < 512) {
        int bm = b & 31, bn = b >> 5;  // bn 0..15
        gemm_tile_bf16<0, u8>(xb + (size_t)bm * 128 * 1024, 1024,
                              wqk + (size_t)bn * 128 * 1024, 1024,
                              qk + (size_t)bm * 128 * 2048 + bn * 128, 2048,
                              0, 16, 1.f, As, Bs, nullptr);
    } else {
        int t = b - 512;
        int bm = t & 7, bn = t >> 3;  // bn 0..31
        gemm_tile_bf16<0, bf16_t>(wvb + (size_t)bm * 128 * 1024, 1024,
                                  xb + (size_t)bn * 128 * 1024, 1024,
                                  vt + (size_t)bm * 128 * 4096 + bn * 128, 4096,
                                  0, 16, 1.f, As, Bs, nullptr);
    }
}

// P~ = exp((Q@K^T)/32) causal 128x128 tiles, fp8, 8 iters, 528 blocks.
// Compact tri grid t = bm(bm+1)/2 + bn; emits per-row partial sums; diagonal
// tiles (bn==bm) zero dead slots [bm+1,32).
__global__ __launch_bounds__(256) void k_sc(const u8* __restrict__ qk,
                                            bf16_t* __restrict__ P,
                                            float* __restrict__ rowsum_part) {
    __shared__ __attribute__((aligned(16))) u8 As[128 * 128];
    __shared__ __attribute__((aligned(16))) u8 Bs[128 * 128];
    __shared__ float sred[128 * 2];
    int t = blockIdx.x;  // 0..527
    int bm = (int)((sqrtf(8.f * (float)t + 1.f) - 1.f) * 0.5f);
    while (bm * (bm + 1) / 2 > t) --bm;
    while ((bm + 1) * (bm + 2) / 2 <= t) ++bm;
    int bn = t - bm * (bm + 1) / 2;  // 0..bm
    scores_tile_fp8(qk + (size_t)bm * 128 * 2048, 2048,
                    qk + 1024 + (size_t)bn * 128 * 2048, 2048,
                    P + (size_t)bm * 128 * 4096 + bn * 128, 4096,
                    0.03125f, As, Bs,
                    rowsum_part + (size_t)bm * 128 * 32 + bn,
                    bm * 128, bn * 128, sred);
    if (bn == bm) {  // zero dead rowsum slots for this row block
        float* rp = rowsum_part + (size_t)bm * 128 * 32;
        int tid = threadIdx.x;
        for (int r = tid >> 4; r < 128; r += 16)
            for (int u = bm + 1 + (tid & 15); u < 32; u += 16)
                rp[r * 32 + u] = 0.f;
    }
}

// O = (P~ @ V) * diag(1/rowsum), bf16, BK=64: nk = 2(bm+1) iters.
// Split-K chunk 16: 80 groups x 8 bn = 640 blocks. Groups ordered by
// DESCENDING length so the 3rd dispatch round (g 64..79) carries only short
// blocks: g0..1 = singles bm7,6; g2..33 = ns4 bm31..24; g34..57 = ns3
// bm23..16; g58..73 = ns2 bm15..8; g74..79 = singles bm5..0. Split
// boundaries (kb = s*nk/ns) unchanged -> k_reduce layout identical.
__global__ __launch_bounds__(256) void k_pv(const bf16_t* __restrict__ P,
                                            const bf16_t* __restrict__ vt,
                                            const float* __restrict__ rowsum_part,
                                            float* __restrict__ out,
                                            float* __restrict__ partials) {
    __shared__ __attribute__((aligned(16))) bf16_t As[128 * 64];
    __shared__ __attribute__((aligned(16))) bf16_t Bs[128 * 64];
    __shared__ float sInv[128];
    int b = blockIdx.x;
    int bn = b & 7, g = b >> 3;
    int bm, s, ns;
    if (g < 2)       { bm = 7 - g;                 s = 0;            ns = 1; }
    else if (g < 34) { int t = g - 2;  bm = 31 - (t >> 2); s = t & 3; ns = 4; }
    else if (g < 58) { int t = g - 34; bm = 23 - t / 3;    s = t % 3; ns = 3; }
    else if (g < 74) { int t = g - 58; bm = 15 - (t >> 1); s = t & 1; ns = 2; }
    else             { bm = 5 - (g - 74);          s = 0;            ns = 1; }
    int nk = 2 * (bm + 1);
    int kb0 = s * nk / ns;
    int kb1 = (s + 1) * nk / ns;

    const bf16_t* A = P + (size_t)bm * 128 * 4096;
    const bf16_t* B = vt + (size_t)bn * 128 * 4096;
    if (ns == 1) {
        int tid = threadIdx.x;
        if (tid < 128)
            sInv[tid] = 1.f / sum32(rowsum_part + (size_t)(bm * 128 + tid) * 32);
        // visibility of sInv covered by the K-loop's __syncthreads (nk >= 2)
        gemm_tile_bf16<2, float>(A, 4096, B, 4096,
                                 out + (size_t)bm * 128 * 1024 + bn * 128, 1024,
                                 kb0, kb1, 1.f, As, Bs, sInv);
    } else {
        int cum = (bm < 16) ? (bm - 8) * 2
                : (bm < 24) ? 16 + (bm - 16) * 3
                            : 40 + (bm - 24) * 4;
        gemm_tile_bf16<0, float>(A, 4096, B, 4096,
                                 partials + ((size_t)(cum + s) * 8 + bn) * 16384, 128,
                                 kb0, kb1, 1.f, As, Bs, nullptr);
    }
}

// out tiles for bm in [8,31]: sum 2..4 fp32 partials, scale by 1/rowsum.
// Compact 3072 blocks: t = b%192 -> (bm-8, bn); p = b/192 -> tile 16th
// (8 rows x 128 cols per block); float4/thread.
__global__ __launch_bounds__(256) void k_reduce(const float* __restrict__ partials,
                                                const float* __restrict__ rowsum_part,
                                                float* __restrict__ out) {
    int b = blockIdx.x;
    int t = b % 192, p = b / 192;
    int bm = t % 24 + 8, bn = t / 24;
    int ns = (bm < 16) ? 2 : (bm < 24) ? 3 : 4;
    int cum = (bm < 16) ? (bm - 8) * 2
            : (bm < 24) ? 16 + (bm - 16) * 3
                        : 40 + (bm - 24) * 4;
    __shared__ float sInv[8];
    int tid = threadIdx.x;
    if (tid < 8) {
        int row = bm * 128 + p * 8 + tid;
        sInv[tid] = 1.f / sum32(rowsum_part + (size_t)row * 32);
    }
    __syncthreads();

    int idx = p * 1024 + tid * 4;
    int lr = idx >> 7, lc = idx & 127;
    float sx = 0.f, sy = 0.f, sz = 0.f, sw = 0.f;
    for (int u = 0; u < ns; ++u) {
        const float4 v = *(const float4*)(partials + ((size_t)(cum + u) * 8 + bn) * 16384 + idx);
        sx += v.x; sy += v.y; sz += v.z; sw += v.w;
    }
    float inv = sInv[lr - p * 8];
    float4 o = {sx * inv, sy * inv, sz * inv, sw * inv};
    *(float4*)(out + (size_t)(bm * 128 + lr) * 1024 + bn * 128 + lc) = o;
}

// fp32 -> bf16 casts: x -> x_bf, Wq|Wk -> Wqk (concat), Wv -> Wv_bf.
__global__ __launch_bounds__(256) void cast_to_bf16(const float* __restrict__ x,
                                                    const float* __restrict__ Wq,
                                                    const float* __restrict__ Wk,
                                                    const float* __restrict__ Wv,
                                                    bf16_t* __restrict__ xb,
                                                    bf16_t* __restrict__ wqk,
                                                    bf16_t* __restrict__ wv) {
    const int NX = (4096 * 1024) / 4;
    const int NW = (1024 * 1024) / 4;
    int idx = blockIdx.x * 256 + threadIdx.x;
    const float* src;
    bf16_t* dst;
    int off;
    if (idx < NX) {
        src = x; dst = xb; off = idx;
    } else if (idx < NX + NW) {
        src = Wq; dst = wqk; off = idx - NX;
    } else if (idx < NX + 2 * NW) {
        src = Wk; dst = wqk + (size_t)NW * 4; off = idx - NX - NW;
    } else {
        src = Wv; dst = wv; off = idx - NX - 2 * NW;
    }
    float4 f = ((const float4*)src)[off];
    bf16x4v o;
    o.x = (bf16_t)f.x; o.y = (bf16_t)f.y; o.z = (bf16_t)f.z; o.w = (bf16_t)f.w;
    *(bf16x4v*)(dst + (size_t)off * 4) = o;
}

extern "C" void kernel_launch(void* const* d_in, const int* in_sizes, int n_in,
                              void* d_out, int out_size, void* d_ws, size_t ws_size,
                              hipStream_t stream) {
    (void)in_sizes; (void)n_in; (void)out_size; (void)ws_size;
    const float* x  = (const float*)d_in[0];
    const float* Wq = (const float*)d_in[1];
    const float* Wk = (const float*)d_in[2];
    const float* Wv = (const float*)d_in[3];
    float* out = (float*)d_out;

    char* ws = (char*)d_ws;
    bf16_t* xb   = (bf16_t*)(ws + (size_t)0);
    bf16_t* wqk  = (bf16_t*)(ws + ((size_t)8 << 20));
    bf16_t* wvb  = (bf16_t*)(ws + ((size_t)12 << 20));
    u8*     qk   = (u8*)(ws + ((size_t)14 << 20));
    bf16_t* vt   = (bf16_t*)(ws + ((size_t)22 << 20));
    bf16_t* P    = (bf16_t*)(ws + ((size_t)30 << 20));
    float* rowsp = (float*)(ws + ((size_t)62 << 20));
    float* parts = (float*)(ws + ((size_t)64 << 20));

    cast_to_bf16<<<7168, 256, 0, stream>>>(x, Wq, Wk, Wv, xb, wqk, wvb);

    // QK (fp8) + all of Vt (768 blocks, exactly 3/CU, uniform)
    k_qkv<<<768, 256, 0, stream>>>(xb, wqk, wvb, qk, vt);

    // P~ = exp((Q@K^T)/32) causal 128x128 (528 blocks, pure scores)
    k_sc<<<528, 256, 0, stream>>>(qk, P, rowsp);

    // out = (P~ @ V) * diag(1/rowsum): split-K chunk 16, length-ordered
    k_pv<<<640, 256, 0, stream>>>(P, vt, rowsp, out, parts);
    k_reduce<<<3072, 256, 0, stream>>>(parts, rowsp, out);
}